// Round 9
// baseline (646.245 us; speedup 1.0000x reference)
//
#include <hip/hip_runtime.h>
#include <hip/hip_bf16.h>

// Problem constants (B=8192, D=128 from reference setup_inputs)
constexpr int Bh = 8192;
constexpr int Nn = 16384;   // 2*B
constexpr int Dd = 128;
constexpr float EPS = 1e-8f;
constexpr float LN2 = 0.69314718056f;

constexpr int K_TILES = 8;          // tiles per block
constexpr int N_TILES = 8256;       // 128x128 upper-tri tiles (incl diag): 128*129/2
constexpr int N_BLOCKS = N_TILES / K_TILES;   // 1032, exact

typedef short bf16x8 __attribute__((ext_vector_type(8)));
typedef float f32x4 __attribute__((ext_vector_type(4)));

// ---- Kernel 1: fp32 -> bf16, scaled by sqrt(2*log2e) so MFMA dot == sim/tau*log2e ----
__global__ __launch_bounds__(256) void convert_kernel(const float4* __restrict__ za,
                                                      const float4* __restrict__ zb,
                                                      ushort* __restrict__ z,
                                                      float* __restrict__ rowsum,
                                                      float* __restrict__ out) {
    const int t = blockIdx.x * 256 + threadIdx.x;        // 0 .. 524287
    constexpr int Q = (Bh * Dd) / 4;                     // 262144 float4 per input
    const float SCL = 1.69864363f;                       // sqrt(2 * 1.4426950409)
    float4 v = (t < Q) ? za[t] : zb[t - Q];
    union { ushort4 u4; __hip_bfloat16 h[4]; } cv;
    cv.h[0] = __float2bfloat16(v.x * SCL);
    cv.h[1] = __float2bfloat16(v.y * SCL);
    cv.h[2] = __float2bfloat16(v.z * SCL);
    cv.h[3] = __float2bfloat16(v.w * SCL);
    ((ushort4*)z)[t] = cv.u4;
    if (t < Nn) rowsum[t] = 0.f;
    if (t == 0) out[0] = 0.f;          // finalize accumulates via atomics
}

// tile index g -> row tile t (128-row granularity): largest t with cum(t)=t*(257-t)/2 <= g
__device__ __forceinline__ int row_tile_of(int g) {
    int t = (int)((257.0f - sqrtf(66049.0f - 8.0f * (float)g)) * 0.5f);
    t = t < 0 ? 0 : (t > 127 ? 127 : t);
    while (t * (257 - t) / 2 > g) --t;
    while ((t + 1) * (256 - t) / 2 <= g) ++t;
    return t;
}

// row-credit flush: reduce rs over the 16 col-lanes, one atomic per row (log2 domain)
__device__ __forceinline__ void flush_rs(float* __restrict__ rowsum, int rowW,
                                         float (&rs)[2][4], int q, int c) {
#pragma unroll
    for (int s = 0; s < 2; ++s)
#pragma unroll
        for (int r = 0; r < 4; ++r) {
            float v = rs[s][r];
            v += __shfl_xor(v, 1);
            v += __shfl_xor(v, 2);
            v += __shfl_xor(v, 4);
            v += __shfl_xor(v, 8);
            if (c == 0) atomicAdd(&rowsum[rowW + s * 16 + q * 4 + r], v);
            rs[s][r] = 0.f;
        }
}

// col-credit flush (deferred one tile): reduce over q, one atomic per col
__device__ __forceinline__ void colflush(float* __restrict__ rowsum,
                                         float (&csumP)[8], int C0P, int lane, int c) {
#pragma unroll
    for (int st = 0; st < 8; ++st) {
        float v = csumP[st];
        v += __shfl_xor(v, 16);
        v += __shfl_xor(v, 32);
        if (lane < 16) atomicAdd(&rowsum[C0P + st * 16 + c], v);
    }
}

// Stage one 128x128 bf16 B-tile (32 KB) into LDS via global_load_lds width-16.
// LDS layout XOR-swizzled via per-lane permutation of the GLOBAL source (m173);
// ds_read_b128 fragment reads are bank-conflict-free (8 words/bank).
__device__ __forceinline__ void stage_tile(const ushort* __restrict__ z, ushort* lbuf,
                                           int C0, int wave, int lane) {
#pragma unroll
    for (int i = 0; i < 8; ++i) {
        const int chunk = wave * 8 + i;              // 32 chunks of 1 KB
        const int r = (chunk << 2) + (lane >> 4);    // row 0..127 (one col of z)
        const int bl = ((lane & 15) ^ (r & 15)) << 4;  // swizzled byte-in-row
        const char* gp = (const char*)z + (((size_t)(C0 + r)) << 8) + bl;
        ushort* lp = lbuf + (chunk << 9);            // wave-uniform LDS base
        __builtin_amdgcn_global_load_lds((const __attribute__((address_space(1))) void*)gp,
                                         (__attribute__((address_space(3))) void*)lp,
                                         16, 0, 0);
    }
}

// ---- Kernel 2 (R9 DECOMPOSITION ROUND):
// V0: R8 verbatim (acc-pipelined, 124.8 us measured) — produces the output.
// V1 (REPS=4): skeleton + softplus(2 trans) + rs accumulate + row flush ONLY.
//     Isolates the softplus+row-reduce cost. Writes rowsum junk (harmless:
//     runs after finalize; convert re-zeros next iteration).
// V2 (REPS=2): V0 with each trans op replaced by ONE plain VALU op of the
//     same count (fma / mul) — isolates the trans-pipe premium (V0 - t2).
// Reading: top-5 shows slowest variant (4*t1 by construction); total dur_us
// closes the 2nd unknown; VGPR_Count disambiguates rows.
// Context: VALUBusy*dur = 62 us of VALU issue vs ~33 us static model ->
// either trans is much slower than 1/4-rate or codegen bloat. This splits it.
template <int V>
__global__ __launch_bounds__(256) void main_kernel(const ushort* __restrict__ z,
                                                   float* __restrict__ rowsum,
                                                   float* __restrict__ pospair) {
    __shared__ ushort ldsb[2][16384];     // 2 x 32 KB B-tile double buffer

    const int tid = threadIdx.x;
    const int wave = tid >> 6;
    const int lane = tid & 63;
    const int q = lane >> 4;        // quad: 0..3
    const int c = lane & 15;        // 0..15
    const int g0 = blockIdx.x * K_TILES;

    // per-lane swizzled LDS fragment offsets: logical 16B-unit (q+4kt) in row c
    int O[4];
#pragma unroll
    for (int kt = 0; kt < 4; ++kt) O[kt] = (c << 8) + ((((q + 4 * kt) ^ c)) << 4);

    const f32x4 Z4 = {0.f, 0.f, 0.f, 0.f};
    constexpr int REPS = (V == 1) ? 4 : (V == 2) ? 2 : 1;

    for (int rep = 0; rep < REPS; ++rep) {
        int tr = row_tile_of(g0);
        int ct = tr + (g0 - tr * (257 - tr) / 2);

        bf16x8 afrag[2][4];
        float rs[2][4];
#pragma unroll
        for (int s = 0; s < 2; ++s)
#pragma unroll
            for (int r = 0; r < 4; ++r) rs[s][r] = 0.f;

        float csumP[8];
        int C0P = 0;
        bool pendP = false;
        int cur_tr = -1, rowW = 0, cur = 0;

        stage_tile(z, &ldsb[0][0], ct << 7, wave, lane);
        __syncthreads();

        for (int j = 0; j < K_TILES; ++j) {
            const int C0 = ct << 7;
            const bool diag = (ct == tr);

            if (tr != cur_tr) {                 // row-panel change: flush + reload A
                if (cur_tr >= 0) flush_rs(rowsum, rowW, rs, q, c);
                cur_tr = tr;
                rowW = (tr << 7) + wave * 32;   // this wave's 32-row base
#pragma unroll
                for (int s = 0; s < 2; ++s) {
                    const ushort* ap = z + (size_t)(rowW + s * 16 + c) * Dd;
#pragma unroll
                    for (int kt = 0; kt < 4; ++kt)
                        afrag[s][kt] = *(const bf16x8*)(ap + kt * 32 + q * 8);
                }
            }

            // deferred col-credit flush from previous tile
            if (V != 1 && pendP) { colflush(rowsum, csumP, C0P, lane, c); pendP = false; }

            // next tile coords + prefetch-stage into the other buffer
            int trN = tr, ctN = ct + 1;
            if (ctN == 128) { trN = tr + 1; ctN = trN; }
            if (j + 1 < K_TILES) stage_tile(z, &ldsb[cur ^ 1][0], ctN << 7, wave, lane);

            const char* lb = (const char*)&ldsb[cur][0];
            float csum[8];
#pragma unroll
            for (int st = 0; st < 8; ++st) csum[st] = 0.f;

            // ---- acc-pipelined phase loop: 9 phases over 8 st's (R8 schedule).
            f32x4 acc[2][2];
#pragma unroll
            for (int st = 0; st < 9; ++st) {
                const int p = st & 1;
                if (st < 8) {
                    bf16x8 bcur[4];
#pragma unroll
                    for (int kt = 0; kt < 4; ++kt)
                        bcur[kt] = *(const bf16x8*)(lb + O[kt] + st * 4096);
#pragma unroll
                    for (int s = 0; s < 2; ++s)
                        acc[p][s] = __builtin_amdgcn_mfma_f32_16x16x32_bf16(afrag[s][0], bcur[0], Z4, 0, 0, 0);
#pragma unroll
                    for (int kt = 1; kt < 4; ++kt) {
#pragma unroll
                        for (int s = 0; s < 2; ++s)
                            acc[p][s] = __builtin_amdgcn_mfma_f32_16x16x32_bf16(afrag[s][kt], bcur[kt], acc[p][s], 0, 0, 0);
                    }
                }
                if (st > 0) {
                    const int stP = st - 1;         // phase being finished
                    const int pp = p ^ 1;
                    const int gc0 = C0 + stP * 16;
#pragma unroll
                    for (int s = 0; s < 2; ++s) {
                        const int R = rowW + s * 16;
                        float sp[4];
#pragma unroll
                        for (int r = 0; r < 4; ++r) {
                            float u = acc[pp][s][r];
                            if constexpr (V == 2) {
                                // trans ops replaced 1:1 by plain VALU ops
                                float e = __builtin_fmaf(u, -0.123f, 0.7f);
                                sp[r] = fmaxf(u, 0.f) + (1.f + e) * 1.4427f;
                            } else {
                                // softplus in log2 domain: max(u,0) + log2(1 + 2^-|u|)
                                float e = __builtin_amdgcn_exp2f(-fabsf(u));
                                sp[r] = fmaxf(u, 0.f) + __builtin_amdgcn_logf(1.f + e);
                            }
                        }
                        if constexpr (V != 1) {
                            if (diag && gc0 == R) {               // zero self-similarity
#pragma unroll
                                for (int r = 0; r < 4; ++r)
                                    if (c == q * 4 + r) sp[r] = 0.f;
                            }
                            if (gc0 == (R ^ Bh)) {                // positive-pair subtile
#pragma unroll
                                for (int r = 0; r < 4; ++r)
                                    if (c == q * 4 + r) pospair[R + q * 4 + r] = sp[r];
                            }
                        }
#pragma unroll
                        for (int r = 0; r < 4; ++r) rs[s][r] += sp[r];
                        if constexpr (V != 1) {
                            if (!diag) csum[stP] += (sp[0] + sp[1]) + (sp[2] + sp[3]);
                        }
                    }
                }
            }

            if (V != 1 && !diag) {    // defer the col-credit atomics past the barrier
#pragma unroll
                for (int st = 0; st < 8; ++st) csumP[st] = csum[st];
                C0P = C0;
                pendP = true;
            }

            __syncthreads();        // drains vmcnt(0): stage + atomics all a tile old
            cur ^= 1;
            tr = trN;
            ct = ctN;
        }

        if (V != 1 && pendP) colflush(rowsum, csumP, C0P, lane, c);
        if (cur_tr >= 0) flush_rs(rowsum, rowW, rs, q, c);
    }
}

// ---- Kernel 3: final loss (log2-domain sums back via ln2), 16 blocks x 1024 ----
__global__ __launch_bounds__(1024) void finalize_kernel(const float* __restrict__ rowsum,
                                                        const float* __restrict__ pospair,
                                                        float* __restrict__ out) {
    __shared__ float red[16];
    const int i = blockIdx.x * 1024 + threadIdx.x;   // 16*1024 == Nn exactly
    float denom = fmaxf(LN2 * rowsum[i], EPS);
    float sp = fmaxf(LN2 * pospair[i & (Bh - 1)], EPS);   // pospair[i]==pospair[i^B]
    float acc = __logf(sp) - __logf(denom);
#pragma unroll
    for (int m = 1; m < 64; m <<= 1) acc += __shfl_xor(acc, m);
    if ((threadIdx.x & 63) == 0) red[threadIdx.x >> 6] = acc;
    __syncthreads();
    if (threadIdx.x < 16) {
        float v = red[threadIdx.x];
        v += __shfl_xor(v, 1);
        v += __shfl_xor(v, 2);
        v += __shfl_xor(v, 4);
        v += __shfl_xor(v, 8);
        if (threadIdx.x == 0) atomicAdd(out, -v / (float)Nn);
    }
}

extern "C" void kernel_launch(void* const* d_in, const int* in_sizes, int n_in,
                              void* d_out, int out_size, void* d_ws, size_t ws_size,
                              hipStream_t stream) {
    const float* za = (const float*)d_in[0];
    const float* zb = (const float*)d_in[1];

    // workspace layout: z_bf16 (4 MB) | rowsum (64 KB) | pospair (32 KB used)
    ushort* z = (ushort*)d_ws;
    float* rowsum = (float*)((char*)d_ws + (size_t)Nn * Dd * 2);
    float* pospair = rowsum + Nn;
    float* out = (float*)d_out;

    convert_kernel<<<2048, 256, 0, stream>>>((const float4*)za, (const float4*)zb, z, rowsum, out);
    main_kernel<0><<<N_BLOCKS, 256, 0, stream>>>(z, rowsum, pospair);
    finalize_kernel<<<16, 1024, 0, stream>>>(rowsum, pospair, out);
    // ---- ablation probes (run after finalize; rowsum/pospair corruption is
    // harmless — convert re-zeros rowsum and V0 rewrites pospair next iter) ----
    main_kernel<1><<<N_BLOCKS, 256, 0, stream>>>(z, rowsum, pospair);
    main_kernel<2><<<N_BLOCKS, 256, 0, stream>>>(z, rowsum, pospair);
}

// Round 10
// 165.218 us; speedup vs baseline: 3.9115x; 3.9115x over previous
//
#include <hip/hip_runtime.h>
#include <hip/hip_bf16.h>

// Problem constants (B=8192, D=128 from reference setup_inputs)
constexpr int Bh = 8192;
constexpr int Nn = 16384;   // 2*B
constexpr int Dd = 128;
constexpr float EPS = 1e-8f;
constexpr float LN2 = 0.69314718056f;

// R10 geometry: 128-row x 64-col half-tiles (16 KB staged B), upper-tri.
// cum2(t) = t*(257-t) half-tiles before row-tile t; total = 128*129 = 16512.
constexpr int K_TILES = 16;         // half-tiles per block
constexpr int N_TILES = 16512;
constexpr int N_BLOCKS = N_TILES / K_TILES;   // 1032, exact

typedef short bf16x8 __attribute__((ext_vector_type(8)));
typedef float f32x4 __attribute__((ext_vector_type(4)));

// ---- Kernel 1: fp32 -> bf16, scaled by sqrt(2*log2e) so MFMA dot == sim/tau*log2e ----
__global__ __launch_bounds__(256) void convert_kernel(const float4* __restrict__ za,
                                                      const float4* __restrict__ zb,
                                                      ushort* __restrict__ z,
                                                      float* __restrict__ rowsum,
                                                      float* __restrict__ out) {
    const int t = blockIdx.x * 256 + threadIdx.x;        // 0 .. 524287
    constexpr int Q = (Bh * Dd) / 4;                     // 262144 float4 per input
    const float SCL = 1.69864363f;                       // sqrt(2 * 1.4426950409)
    float4 v = (t < Q) ? za[t] : zb[t - Q];
    union { ushort4 u4; __hip_bfloat16 h[4]; } cv;
    cv.h[0] = __float2bfloat16(v.x * SCL);
    cv.h[1] = __float2bfloat16(v.y * SCL);
    cv.h[2] = __float2bfloat16(v.z * SCL);
    cv.h[3] = __float2bfloat16(v.w * SCL);
    ((ushort4*)z)[t] = cv.u4;
    if (t < Nn) rowsum[t] = 0.f;
    if (t == 0) out[0] = 0.f;          // finalize accumulates via atomics
}

// half-tile index g -> row tile t: largest t with cum2(t) = t*(257-t) <= g
__device__ __forceinline__ int row_tile_of(int g) {
    int t = (int)((257.0f - sqrtf((float)(66049 - 4 * g))) * 0.5f);
    t = t < 0 ? 0 : (t > 127 ? 127 : t);
    while (t * (257 - t) > g) --t;
    while ((t + 1) * (256 - t) <= g) ++t;
    return t;
}

// row-credit flush: reduce rs over the 16 col-lanes, one atomic per row
__device__ __forceinline__ void flush_rs(float* __restrict__ rowsum, int rowW,
                                         float (&rs)[2][4], int q, int c) {
#pragma unroll
    for (int s = 0; s < 2; ++s)
#pragma unroll
        for (int r = 0; r < 4; ++r) {
            float v = rs[s][r];
            v += __shfl_xor(v, 1);
            v += __shfl_xor(v, 2);
            v += __shfl_xor(v, 4);
            v += __shfl_xor(v, 8);
            if (c == 0) atomicAdd(&rowsum[rowW + s * 16 + q * 4 + r], v);
            rs[s][r] = 0.f;
        }
}

// col-credit flush (deferred one half-tile): reduce over q, one atomic per col
__device__ __forceinline__ void colflush(float* __restrict__ rowsum,
                                         float (&csumP)[4], int C0P, int lane, int c) {
#pragma unroll
    for (int st = 0; st < 4; ++st) {
        float v = csumP[st];
        v += __shfl_xor(v, 16);
        v += __shfl_xor(v, 32);
        if (lane < 16) atomicAdd(&rowsum[C0P + st * 16 + c], v);
    }
}

// Stage one 64-col x 128-K bf16 B half-tile (16 KB) into LDS via
// global_load_lds width-16. LDS XOR-swizzled via per-lane permutation of the
// GLOBAL source (m173); ds_read_b128 fragment reads stay bank-conflict-free.
// 4 waves x 4 chunks of 1 KB = 16 KB; each "row" = one z-vector (256 B).
__device__ __forceinline__ void stage_tile(const ushort* __restrict__ z, ushort* lbuf,
                                           int C0, int wave, int lane) {
#pragma unroll
    for (int i = 0; i < 4; ++i) {
        const int chunk = wave * 4 + i;              // 16 chunks of 1 KB
        const int r = (chunk << 2) + (lane >> 4);    // col 0..63 of this half-tile
        const int bl = ((lane & 15) ^ (r & 15)) << 4;  // swizzled byte-in-row
        const char* gp = (const char*)z + (((size_t)(C0 + r)) << 8) + bl;
        ushort* lp = lbuf + (chunk << 9);            // wave-uniform LDS base
        __builtin_amdgcn_global_load_lds((const __attribute__((address_space(1))) void*)gp,
                                         (__attribute__((address_space(3))) void*)lp,
                                         16, 0, 0);
    }
}

// ---- Kernel 2: R8 structure at 64-col half-tiles -> 4 blocks/CU.
// R9 decomposition of the 125 us: skeleton 49 + non-trans VALU 28 + TRANS
// PREMIUM 48 (static trans issue only ~14 -> ~34 us is latency stall,
// unhidden at 2 waves/SIMD). R1/R4's "occupancy doesn't help" both conflated
// occupancy with halved rows/wave; this round doubles waves/SIMD (32 KB LDS
// -> 4 blocks/CU) at UNCHANGED per-wave geometry: 32 rows/wave, full-K
// A-frags, same fragment addressing (row = st*16+c, row&15 == c), same
// epilogue formula, same acc-pipeline, same atomic counts.
__global__ __launch_bounds__(256) void main_kernel(const ushort* __restrict__ z,
                                                   float* __restrict__ rowsum,
                                                   float* __restrict__ pospair) {
    __shared__ ushort ldsb[2][8192];      // 2 x 16 KB B half-tile double buffer

    const int tid = threadIdx.x;
    const int wave = tid >> 6;
    const int lane = tid & 63;
    const int q = lane >> 4;        // quad: 0..3
    const int c = lane & 15;        // 0..15
    const int g0 = blockIdx.x * K_TILES;

    int tr = row_tile_of(g0);
    int ct = 2 * tr + (g0 - tr * (257 - tr));   // col half-tile 0..255

    // per-lane swizzled LDS fragment offsets: logical 16B-unit (q+4kt) in row c
    int O[4];
#pragma unroll
    for (int kt = 0; kt < 4; ++kt) O[kt] = (c << 8) + ((((q + 4 * kt) ^ c)) << 4);

    bf16x8 afrag[2][4];
    float rs[2][4];
#pragma unroll
    for (int s = 0; s < 2; ++s)
#pragma unroll
        for (int r = 0; r < 4; ++r) rs[s][r] = 0.f;

    const f32x4 Z4 = {0.f, 0.f, 0.f, 0.f};

    float csumP[4];
    int C0P = 0;
    bool pendP = false;
    int cur_tr = -1, rowW = 0, cur = 0;

    stage_tile(z, &ldsb[0][0], ct << 6, wave, lane);
    __syncthreads();

    for (int j = 0; j < K_TILES; ++j) {
        const int C0 = ct << 6;                 // column base (64-wide)
        const bool diag = ((ct >> 1) == tr);    // half-tile inside the diagonal 128x128

        if (tr != cur_tr) {                 // row-panel change: flush + reload A
            if (cur_tr >= 0) flush_rs(rowsum, rowW, rs, q, c);
            cur_tr = tr;
            rowW = (tr << 7) + wave * 32;   // this wave's 32-row base
#pragma unroll
            for (int s = 0; s < 2; ++s) {
                const ushort* ap = z + (size_t)(rowW + s * 16 + c) * Dd;
#pragma unroll
                for (int kt = 0; kt < 4; ++kt)
                    afrag[s][kt] = *(const bf16x8*)(ap + kt * 32 + q * 8);
            }
        }

        // deferred col-credit flush from previous half-tile
        if (pendP) { colflush(rowsum, csumP, C0P, lane, c); pendP = false; }

        // next half-tile coords + prefetch-stage into the other buffer
        int trN = tr, ctN = ct + 1;
        if (ctN == 256) { trN = tr + 1; ctN = 2 * trN; }
        if (j + 1 < K_TILES) stage_tile(z, &ldsb[cur ^ 1][0], ctN << 6, wave, lane);

        const char* lb = (const char*)&ldsb[cur][0];
        float csum[4];
#pragma unroll
        for (int st = 0; st < 4; ++st) csum[st] = 0.f;

        // ---- acc-pipelined phase loop: 5 phases over 4 st's (R8 schedule).
        f32x4 acc[2][2];
#pragma unroll
        for (int st = 0; st < 5; ++st) {
            const int p = st & 1;
            if (st < 4) {
                bf16x8 bcur[4];
#pragma unroll
                for (int kt = 0; kt < 4; ++kt)
                    bcur[kt] = *(const bf16x8*)(lb + O[kt] + st * 4096);
#pragma unroll
                for (int s = 0; s < 2; ++s)
                    acc[p][s] = __builtin_amdgcn_mfma_f32_16x16x32_bf16(afrag[s][0], bcur[0], Z4, 0, 0, 0);
#pragma unroll
                for (int kt = 1; kt < 4; ++kt) {
#pragma unroll
                    for (int s = 0; s < 2; ++s)
                        acc[p][s] = __builtin_amdgcn_mfma_f32_16x16x32_bf16(afrag[s][kt], bcur[kt], acc[p][s], 0, 0, 0);
                }
            }
            if (st > 0) {
                const int stP = st - 1;         // phase being finished
                const int pp = p ^ 1;
                const int gc0 = C0 + stP * 16;
#pragma unroll
                for (int s = 0; s < 2; ++s) {
                    const int R = rowW + s * 16;
                    float sp[4];
#pragma unroll
                    for (int r = 0; r < 4; ++r) {
                        float u = acc[pp][s][r];
                        // softplus scaled by log2e: max(u,0) + log2(1 + 2^-|u|)
                        float e = __builtin_amdgcn_exp2f(-fabsf(u));
                        sp[r] = fmaxf(u, 0.f) + __builtin_amdgcn_logf(1.f + e);
                    }
                    if (diag && gc0 == R) {               // zero self-similarity
#pragma unroll
                        for (int r = 0; r < 4; ++r)
                            if (c == q * 4 + r) sp[r] = 0.f;
                    }
                    if (gc0 == (R ^ Bh)) {                // positive-pair subtile
#pragma unroll
                        for (int r = 0; r < 4; ++r)
                            if (c == q * 4 + r) pospair[R + q * 4 + r] = sp[r];
                    }
#pragma unroll
                    for (int r = 0; r < 4; ++r) rs[s][r] += sp[r];
                    if (!diag) csum[stP] += (sp[0] + sp[1]) + (sp[2] + sp[3]);
                }
            }
        }

        if (!diag) {    // defer the col-credit atomics past the barrier
#pragma unroll
            for (int st = 0; st < 4; ++st) csumP[st] = csum[st];
            C0P = C0;
            pendP = true;
        }

        __syncthreads();        // drains vmcnt(0): stage + atomics all a phase old
        cur ^= 1;
        tr = trN;
        ct = ctN;
    }

    if (pendP) colflush(rowsum, csumP, C0P, lane, c);
    if (cur_tr >= 0) flush_rs(rowsum, rowW, rs, q, c);
}

// ---- Kernel 3: final loss (log2-domain sums back via ln2), 16 blocks x 1024 ----
__global__ __launch_bounds__(1024) void finalize_kernel(const float* __restrict__ rowsum,
                                                        const float* __restrict__ pospair,
                                                        float* __restrict__ out) {
    __shared__ float red[16];
    const int i = blockIdx.x * 1024 + threadIdx.x;   // 16*1024 == Nn exactly
    float denom = fmaxf(LN2 * rowsum[i], EPS);
    float sp = fmaxf(LN2 * pospair[i & (Bh - 1)], EPS);   // pospair[i]==pospair[i^B]
    float acc = __logf(sp) - __logf(denom);
#pragma unroll
    for (int m = 1; m < 64; m <<= 1) acc += __shfl_xor(acc, m);
    if ((threadIdx.x & 63) == 0) red[threadIdx.x >> 6] = acc;
    __syncthreads();
    if (threadIdx.x < 16) {
        float v = red[threadIdx.x];
        v += __shfl_xor(v, 1);
        v += __shfl_xor(v, 2);
        v += __shfl_xor(v, 4);
        v += __shfl_xor(v, 8);
        if (threadIdx.x == 0) atomicAdd(out, -v / (float)Nn);
    }
}

extern "C" void kernel_launch(void* const* d_in, const int* in_sizes, int n_in,
                              void* d_out, int out_size, void* d_ws, size_t ws_size,
                              hipStream_t stream) {
    const float* za = (const float*)d_in[0];
    const float* zb = (const float*)d_in[1];

    // workspace layout: z_bf16 (4 MB) | rowsum (64 KB) | pospair (32 KB used)
    ushort* z = (ushort*)d_ws;
    float* rowsum = (float*)((char*)d_ws + (size_t)Nn * Dd * 2);
    float* pospair = rowsum + Nn;
    float* out = (float*)d_out;

    convert_kernel<<<2048, 256, 0, stream>>>((const float4*)za, (const float4*)zb, z, rowsum, out);
    main_kernel<<<N_BLOCKS, 256, 0, stream>>>(z, rowsum, pospair);
    finalize_kernel<<<16, 1024, 0, stream>>>(rowsum, pospair, out);
}